// Round 1
// 777.719 us; speedup vs baseline: 1.0712x; 1.0712x over previous
//
#include <hip/hip_runtime.h>
#include <hip/hip_bf16.h>

#define B_ 256
#define F_ 2048
#define M_ 65536
#define C_ 8000
#define TEMP_ 0.05f
#define KSPLIT 4

typedef __attribute__((ext_vector_type(8))) short short8;
typedef __attribute__((ext_vector_type(4))) float f32x4;

__device__ inline unsigned short f2bf(float f) {
  union { float f; unsigned u; } v; v.f = f;
  unsigned r = v.u + 0x7fffu + ((v.u >> 16) & 1u);
  return (unsigned short)(r >> 16);
}

// --- K1: L2-normalize rows of results, emit bf16 [B][F]; also zero counts ---
__global__ void k_norm(const float* __restrict__ R, unsigned short* __restrict__ xb,
                       int* __restrict__ counts) {
  int b = blockIdx.x, t = threadIdx.x;
  int g = b * 256 + t;
  if (g < C_) counts[g] = 0;  // 256 blocks x 256 threads = 65536 >= C_
  const float4* row = (const float4*)(R + (size_t)b * F_);
  float4 v0 = row[t];
  float4 v1 = row[t + 256];
  float ss = v0.x*v0.x + v0.y*v0.y + v0.z*v0.z + v0.w*v0.w
           + v1.x*v1.x + v1.y*v1.y + v1.z*v1.z + v1.w*v1.w;
  __shared__ float red[256];
  red[t] = ss; __syncthreads();
  for (int s = 128; s > 0; s >>= 1) { if (t < s) red[t] += red[t + s]; __syncthreads(); }
  float inv = rsqrtf(red[0]);
  ushort4 o0, o1;
  o0.x = f2bf(v0.x * inv); o0.y = f2bf(v0.y * inv); o0.z = f2bf(v0.z * inv); o0.w = f2bf(v0.w * inv);
  o1.x = f2bf(v1.x * inv); o1.y = f2bf(v1.y * inv); o1.z = f2bf(v1.z * inv); o1.w = f2bf(v1.w * inv);
  ushort4* ob = (ushort4*)(xb + (size_t)b * F_);
  ob[t] = o0; ob[t + 256] = o1;
}

// --- K2: histogram of labels ---
__global__ void k_hist(const int* __restrict__ labels, int* __restrict__ counts) {
  int m = blockIdx.x * 256 + threadIdx.x;
  atomicAdd(&counts[labels[m]], 1);
}

// --- K3: exclusive prefix sum over counts (single block); also zero cursor ---
__global__ void k_scan(const int* __restrict__ counts, int* __restrict__ offsets,
                       int* __restrict__ cursor) {
  int t = threadIdx.x;
  int base = t * 32;
  int pre[32];
  int run = 0;
  for (int j = 0; j < 32; j++) {
    int idx = base + j;
    pre[j] = run;
    run += (idx < C_) ? counts[idx] : 0;
  }
  __shared__ int sc[256];
  sc[t] = run; __syncthreads();
  for (int off = 1; off < 256; off <<= 1) {
    int x = (t >= off) ? sc[t - off] : 0;
    __syncthreads();
    sc[t] += x;
    __syncthreads();
  }
  int excl = sc[t] - run;
  for (int j = 0; j < 32; j++) {
    int idx = base + j;
    if (idx < C_) { offsets[idx] = excl + pre[j]; cursor[idx] = 0; }
  }
}

// --- K4: scatter member indices per cluster ---
__global__ void k_scatter(const int* __restrict__ labels, const int* __restrict__ offsets,
                          int* __restrict__ cursor, int* __restrict__ order) {
  int m = blockIdx.x * 256 + threadIdx.x;
  int l = labels[m];
  int pos = atomicAdd(&cursor[l], 1);
  order[offsets[l] + pos] = m;
}

// --- K5: per-cluster feature sum, scaled by 1/(TEMP*count), emit bf16 [C][F] ---
// 2-deep member unroll: 4 outstanding 16B loads/thread for better MLP.
__global__ void k_csum(const float* __restrict__ feats, const int* __restrict__ counts,
                       const int* __restrict__ offsets, const int* __restrict__ order,
                       unsigned short* __restrict__ sb) {
  int c = blockIdx.x, t = threadIdx.x;
  int cnt = counts[c], off = offsets[c];
  float4 a0 = {0.f,0.f,0.f,0.f}, a1 = {0.f,0.f,0.f,0.f};
  float4 c0 = {0.f,0.f,0.f,0.f}, c1 = {0.f,0.f,0.f,0.f};
  __shared__ int mlist[256];
  for (int bas = 0; bas < cnt; bas += 256) {
    int n = cnt - bas; if (n > 256) n = 256;
    if (t < n) mlist[t] = order[off + bas + t];
    __syncthreads();
    int i = 0;
    for (; i + 2 <= n; i += 2) {
      const float4* r0 = (const float4*)(feats + (size_t)mlist[i] * F_);
      const float4* r1 = (const float4*)(feats + (size_t)mlist[i + 1] * F_);
      float4 x0 = r0[t], x1 = r0[t + 256];
      float4 y0 = r1[t], y1 = r1[t + 256];
      a0.x += x0.x; a0.y += x0.y; a0.z += x0.z; a0.w += x0.w;
      a1.x += x1.x; a1.y += x1.y; a1.z += x1.z; a1.w += x1.w;
      c0.x += y0.x; c0.y += y0.y; c0.z += y0.z; c0.w += y0.w;
      c1.x += y1.x; c1.y += y1.y; c1.z += y1.z; c1.w += y1.w;
    }
    if (i < n) {
      const float4* r0 = (const float4*)(feats + (size_t)mlist[i] * F_);
      float4 x0 = r0[t], x1 = r0[t + 256];
      a0.x += x0.x; a0.y += x0.y; a0.z += x0.z; a0.w += x0.w;
      a1.x += x1.x; a1.y += x1.y; a1.z += x1.z; a1.w += x1.w;
    }
    __syncthreads();
  }
  a0.x += c0.x; a0.y += c0.y; a0.z += c0.z; a0.w += c0.w;
  a1.x += c1.x; a1.y += c1.y; a1.z += c1.z; a1.w += c1.w;
  float scale = (cnt > 0) ? 1.0f / (TEMP_ * (float)cnt) : 0.0f;
  ushort4 o0, o1;
  o0.x = f2bf(a0.x * scale); o0.y = f2bf(a0.y * scale); o0.z = f2bf(a0.z * scale); o0.w = f2bf(a0.w * scale);
  o1.x = f2bf(a1.x * scale); o1.y = f2bf(a1.y * scale); o1.z = f2bf(a1.z * scale); o1.w = f2bf(a1.w * scale);
  ushort4* ob = (ushort4*)(sb + (size_t)c * F_);
  ob[t] = o0; ob[t + 256] = o1;
}

// --- K6: simp[kz][B][C] = partial of x_bf16 . sum_bf16^T over K-chunk kz ---
// Split-K=4: grid (2,63,4) = 504 blocks ~ 2/CU (vs 126 = 1 wave/SIMD before).
#define BK 64
#define SK 72  // padded LDS row stride in shorts (144B -> 2-way bank alias, free)

__global__ __launch_bounds__(256) void k_gemm(const unsigned short* __restrict__ xb,
                                              const unsigned short* __restrict__ sb,
                                              float* __restrict__ simp) {
  __shared__ __align__(16) short As[128 * SK];
  __shared__ __align__(16) short Bs[128 * SK];
  int t = threadIdx.x;
  int b0 = blockIdx.x * 128;
  int c0 = blockIdx.y * 128;
  int kz = blockIdx.z;
  int k_begin = kz * (F_ / KSPLIT);
  int k_end = k_begin + (F_ / KSPLIT);
  int wave = t >> 6, lane = t & 63;
  int wr = (wave >> 1) * 64, wc = (wave & 1) * 64;
  int m = lane & 15, q = lane >> 4;
  f32x4 acc[4][4];
  for (int i = 0; i < 4; i++)
    for (int j = 0; j < 4; j++)
      acc[i][j] = (f32x4){0.f, 0.f, 0.f, 0.f};

  for (int kk = k_begin; kk < k_end; kk += BK) {
    __syncthreads();
    for (int i = 0; i < 4; i++) {
      int cid = t + i * 256;
      int row = cid >> 3, cc = cid & 7;
      short8 av = *(const short8*)(xb + (size_t)(b0 + row) * F_ + kk + cc * 8);
      *(short8*)(As + row * SK + cc * 8) = av;
      int gc = c0 + row;
      short8 bv = {0, 0, 0, 0, 0, 0, 0, 0};
      if (gc < C_) bv = *(const short8*)(sb + (size_t)gc * F_ + kk + cc * 8);
      *(short8*)(Bs + row * SK + cc * 8) = bv;
    }
    __syncthreads();
    for (int ks = 0; ks < 2; ks++) {
      int kof = ks * 32 + q * 8;
      short8 af[4], bfr[4];
      for (int i = 0; i < 4; i++)
        af[i] = *(const short8*)(As + (wr + i * 16 + m) * SK + kof);
      for (int j = 0; j < 4; j++)
        bfr[j] = *(const short8*)(Bs + (wc + j * 16 + m) * SK + kof);
      for (int i = 0; i < 4; i++)
        for (int j = 0; j < 4; j++)
          acc[i][j] = __builtin_amdgcn_mfma_f32_16x16x32_bf16(af[i], bfr[j], acc[i][j], 0, 0, 0);
    }
  }
  float* sim = simp + (size_t)kz * B_ * C_;
  for (int i = 0; i < 4; i++) {
    for (int j = 0; j < 4; j++) {
      int col = c0 + wc + j * 16 + m;
      if (col < C_) {
        int rbase = b0 + wr + i * 16 + q * 4;
        f32x4 v = acc[i][j];
        sim[(size_t)(rbase + 0) * C_ + col] = v[0];
        sim[(size_t)(rbase + 1) * C_ + col] = v[1];
        sim[(size_t)(rbase + 2) * C_ + col] = v[2];
        sim[(size_t)(rbase + 3) * C_ + col] = v[3];
      }
    }
  }
}

// --- K7: sum split-K partials + masked softmax + NLL per batch row ---
__global__ void k_loss(const float* __restrict__ simp, const int* __restrict__ counts,
                       const int* __restrict__ labels, const int* __restrict__ indexes,
                       float* __restrict__ lossb) {
  int b = blockIdx.x, t = threadIdx.x;
  int tb = labels[indexes[b]];
  const float* s0 = simp + (size_t)b * C_;
  const float* s1 = s0 + (size_t)B_ * C_;
  const float* s2 = s1 + (size_t)B_ * C_;
  const float* s3 = s2 + (size_t)B_ * C_;
  __shared__ float sst;
  __shared__ float red[256];
  float sum = 0.f;
  for (int c = t; c < C_; c += 256) {
    float v = s0[c] + s1[c] + s2[c] + s3[c];
    float e = (counts[c] > 0) ? __expf(v) : 0.f;
    sum += e;
    if (c == tb) sst = e;
  }
  red[t] = sum; __syncthreads();
  for (int s = 128; s > 0; s >>= 1) { if (t < s) red[t] += red[t + s]; __syncthreads(); }
  if (t == 0) {
    float p = sst / (red[0] + 1e-6f);
    lossb[b] = -logf(p + 1e-6f);
  }
}

// --- K8: mean over batch ---
__global__ void k_mean(const float* __restrict__ lossb, float* __restrict__ out) {
  int t = threadIdx.x;
  __shared__ float red[256];
  red[t] = lossb[t]; __syncthreads();
  for (int s = 128; s > 0; s >>= 1) { if (t < s) red[t] += red[t + s]; __syncthreads(); }
  if (t == 0) out[0] = red[0] * (1.0f / 256.0f);
}

extern "C" void kernel_launch(void* const* d_in, const int* in_sizes, int n_in,
                              void* d_out, int out_size, void* d_ws, size_t ws_size,
                              hipStream_t stream) {
  const float* results  = (const float*)d_in[0];
  const int*   indexes  = (const int*)d_in[1];
  const float* features = (const float*)d_in[2];
  const int*   labels   = (const int*)d_in[3];
  float* out = (float*)d_out;

  // ---- workspace budget check (prevents OOB writes killing the container) ----
  // xb 1.0MB + sbf 32.8MB + 3*32KB + order 256KB + simp 32.8MB + lossb 1KB ~= 67MB
  const size_t REQ = (((size_t)B_ * F_ * 2 + 255) & ~(size_t)255)
                   + (((size_t)C_ * F_ * 2 + 255) & ~(size_t)255)
                   + 3 * (((size_t)C_ * 4 + 255) & ~(size_t)255)
                   + (((size_t)M_ * 4 + 255) & ~(size_t)255)
                   + (((size_t)KSPLIT * B_ * C_ * 4 + 255) & ~(size_t)255)
                   + (((size_t)B_ * 4 + 255) & ~(size_t)255);
  if (ws_size < REQ) {
    hipMemsetAsync(d_out, 0, (size_t)out_size * 4, stream);
    return;
  }

  char* p = (char*)d_ws;
  auto carve = [&](size_t bytes) {
    char* r = p;
    p += (bytes + 255) & ~(size_t)255;
    return r;
  };
  unsigned short* xb  = (unsigned short*)carve((size_t)B_ * F_ * 2);   // 1 MB
  unsigned short* sbf = (unsigned short*)carve((size_t)C_ * F_ * 2);   // 32.8 MB
  int* counts  = (int*)carve((size_t)C_ * 4);
  int* offsets = (int*)carve((size_t)C_ * 4);
  int* cursor  = (int*)carve((size_t)C_ * 4);
  int* order   = (int*)carve((size_t)M_ * 4);
  float* simp  = (float*)carve((size_t)KSPLIT * B_ * C_ * 4);          // 32.8 MB
  float* lossb = (float*)carve((size_t)B_ * 4);

  k_norm<<<B_, 256, 0, stream>>>(results, xb, counts);
  k_hist<<<M_ / 256, 256, 0, stream>>>(labels, counts);
  k_scan<<<1, 256, 0, stream>>>(counts, offsets, cursor);
  k_scatter<<<M_ / 256, 256, 0, stream>>>(labels, offsets, cursor, order);
  k_csum<<<C_, 256, 0, stream>>>(features, counts, offsets, order, sbf);
  dim3 g(2, 63, KSPLIT);
  k_gemm<<<g, 256, 0, stream>>>(xb, sbf, simp);
  k_loss<<<B_, 256, 0, stream>>>(simp, counts, labels, indexes, lossb);
  k_mean<<<1, 256, 0, stream>>>(lossb, out);
}